// Round 3
// baseline (483.168 us; speedup 1.0000x reference)
//
#include <hip/hip_runtime.h>
#include <math.h>

#define DIM   2048
#define NEXP  64
#define NGRP  8
#define GSIZE 8
#define TOPK  8
#define TOPKG 4

#define TM    32           // tokens per block (kernel 1)
#define TK    32           // K-tile
#define TPB   256
#define NT    (DIM / TK)   // 64 K-tiles
#define NHT   (NT / 2)     // 32 tiles per K-split half

// margin thresholds (fp32 score scale). Blocked-fp32 accumulation error is
// ~5e-7 rms / ~4e-6 worst on logits -> ~1e-6 on scores. np reference error is
// similar. 4e-5 gives ~40x safety; expected flag rate ~3%.
#define TAU_E 4e-5f
#define TAU_G 8e-5f
#define NEG_INF (-3.4e38f)

#define T2    8            // tokens per fixup block (kernel 2)
#define WLOFF 16           // worklist token ids start at wl[WLOFF]; wl[0]=count

__global__ void zero_wl_kernel(int* wl) {
    if (threadIdx.x < WLOFF) wl[threadIdx.x] = 0;
}

// ---------------- kernel 1: fp32 GEMM + routing + margin flag ----------------
__global__ __launch_bounds__(TPB) void gate_f32_kernel(
    const float* __restrict__ x,
    const float* __restrict__ W,
    const float* __restrict__ b,
    const float* __restrict__ bias,
    float* __restrict__ out_w,
    float* __restrict__ out_i,
    int* __restrict__ wl)
{
    // rows are 16B multiples and arrays 16B aligned -> ds_read_b128 legal
    __shared__ __align__(16) float sA[2][TK][TM + 4];    // [half][k][token]
    __shared__ __align__(16) float sB[2][TK][NEXP + 4];  // [half][k][expert]
    __shared__ float sS [TM][NEXP + 1];                  // score = sigmoid + bias
    __shared__ float sWt[TM][NEXP + 1];                  // sigmoid only
    __shared__ float sMrg[TM][NEXP];                     // half-1 partial sums

    const int tid  = threadIdx.x;
    const int h    = tid >> 7;          // K-split half: waves 0-1 -> 0, 2-3 -> 1
    const int i128 = tid & 127;
    const int ty   = (tid >> 4) & 7;    // token group (4 tokens)
    const int tx   = tid & 15;          // expert group (4 experts)
    const int tok0 = blockIdx.x * TM;

    // staging: each half (128 thr) stages its own tile.
    // x tile: 32 rows x 32 k = 256 float4 -> 2 per thread (rows rr, rr+16)
    // W tile: 64 rows x 32 k = 512 float4 -> 4 per thread (rows rr+16p)
    const int k4 = (i128 & 7) * 4;
    const int rr = i128 >> 3;           // 0..15

    const float* xp0 = x + (size_t)(tok0 + rr)      * DIM + k4;
    const float* xp1 = x + (size_t)(tok0 + rr + 16) * DIM + k4;
    const float* wp0 = W + (size_t)(rr)      * DIM + k4;
    const float* wp1 = W + (size_t)(rr + 16) * DIM + k4;
    const float* wp2 = W + (size_t)(rr + 32) * DIM + k4;
    const float* wp3 = W + (size_t)(rr + 48) * DIM + k4;

    int kb = h * TK;
    float4 pa0 = *(const float4*)(xp0 + kb);
    float4 pa1 = *(const float4*)(xp1 + kb);
    float4 pw0 = *(const float4*)(wp0 + kb);
    float4 pw1 = *(const float4*)(wp1 + kb);
    float4 pw2 = *(const float4*)(wp2 + kb);
    float4 pw3 = *(const float4*)(wp3 + kb);

    float acc[4][4] = {{0.f,0.f,0.f,0.f},{0.f,0.f,0.f,0.f},
                       {0.f,0.f,0.f,0.f},{0.f,0.f,0.f,0.f}};

    for (int it = 0; it < NHT; ++it) {
        sA[h][k4+0][rr]    = pa0.x; sA[h][k4+1][rr]    = pa0.y;
        sA[h][k4+2][rr]    = pa0.z; sA[h][k4+3][rr]    = pa0.w;
        sA[h][k4+0][rr+16] = pa1.x; sA[h][k4+1][rr+16] = pa1.y;
        sA[h][k4+2][rr+16] = pa1.z; sA[h][k4+3][rr+16] = pa1.w;
        sB[h][k4+0][rr]    = pw0.x; sB[h][k4+1][rr]    = pw0.y;
        sB[h][k4+2][rr]    = pw0.z; sB[h][k4+3][rr]    = pw0.w;
        sB[h][k4+0][rr+16] = pw1.x; sB[h][k4+1][rr+16] = pw1.y;
        sB[h][k4+2][rr+16] = pw1.z; sB[h][k4+3][rr+16] = pw1.w;
        sB[h][k4+0][rr+32] = pw2.x; sB[h][k4+1][rr+32] = pw2.y;
        sB[h][k4+2][rr+32] = pw2.z; sB[h][k4+3][rr+32] = pw2.w;
        sB[h][k4+0][rr+48] = pw3.x; sB[h][k4+1][rr+48] = pw3.y;
        sB[h][k4+2][rr+48] = pw3.z; sB[h][k4+3][rr+48] = pw3.w;
        __syncthreads();

        if (it + 1 < NHT) {
            kb += 2 * TK;
            pa0 = *(const float4*)(xp0 + kb);
            pa1 = *(const float4*)(xp1 + kb);
            pw0 = *(const float4*)(wp0 + kb);
            pw1 = *(const float4*)(wp1 + kb);
            pw2 = *(const float4*)(wp2 + kb);
            pw3 = *(const float4*)(wp3 + kb);
        }

        // tile-blocked accumulation (error control: 32-term partials)
        float at[4][4] = {{0.f,0.f,0.f,0.f},{0.f,0.f,0.f,0.f},
                          {0.f,0.f,0.f,0.f},{0.f,0.f,0.f,0.f}};
#pragma unroll
        for (int kk = 0; kk < TK; ++kk) {
            float4 av = *(const float4*)&sA[h][kk][ty * 4];
            float4 bv = *(const float4*)&sB[h][kk][tx * 4];
            float a4[4] = {av.x, av.y, av.z, av.w};
            float b4[4] = {bv.x, bv.y, bv.z, bv.w};
#pragma unroll
            for (int i = 0; i < 4; ++i)
#pragma unroll
                for (int j = 0; j < 4; ++j)
                    at[i][j] += a4[i] * b4[j];
        }
#pragma unroll
        for (int i = 0; i < 4; ++i)
#pragma unroll
            for (int j = 0; j < 4; ++j)
                acc[i][j] += at[i][j];
        __syncthreads();
    }

    // merge K-split halves
    if (h == 1) {
#pragma unroll
        for (int i = 0; i < 4; ++i)
#pragma unroll
            for (int j = 0; j < 4; ++j)
                sMrg[ty * 4 + i][tx * 4 + j] = acc[i][j];
    }
    __syncthreads();

    if (h == 0) {
        float bv4[4], bi4[4];
#pragma unroll
        for (int j = 0; j < 4; ++j) {
            bv4[j] = b[tx * 4 + j];
            bi4[j] = bias[tx * 4 + j];
        }
#pragma unroll
        for (int i = 0; i < 4; ++i) {
            const int t = ty * 4 + i;
#pragma unroll
            for (int j = 0; j < 4; ++j) {
                const int e = tx * 4 + j;
                const float logit = (acc[i][j] + sMrg[t][e]) + bv4[j];
                const float wv = 1.0f / (1.0f + expf(-logit));
                sWt[t][e] = wv;
                sS[t][e]  = wv + bi4[j];
            }
        }
    }
    __syncthreads();

    // routing + margin flagging: thread t per token
    if (tid < TM) {
        const int t = tid;

        float gs[NGRP];
#pragma unroll
        for (int g = 0; g < NGRP; ++g) {
            float m1 = NEG_INF, m2 = NEG_INF;
#pragma unroll
            for (int j = 0; j < GSIZE; ++j) {
                const float v = sS[t][g * GSIZE + j];
                if (v > m1) { m2 = m1; m1 = v; }
                else if (v > m2) { m2 = v; }
            }
            gs[g] = m1 + m2;
        }

        unsigned gmask = 0u;
        float g4val = NEG_INF;
        for (int r = 0; r < TOPKG; ++r) {
            float best = NEG_INF; int bi = 0;
#pragma unroll
            for (int g = 0; g < NGRP; ++g) {
                const float v = ((gmask >> g) & 1u) ? NEG_INF : gs[g];
                if (v > best) { best = v; bi = g; }
            }
            gmask |= 1u << bi;
            g4val = best;
        }
        float m5 = NEG_INF;
#pragma unroll
        for (int g = 0; g < NGRP; ++g)
            if (!((gmask >> g) & 1u) && gs[g] > m5) m5 = gs[g];
        const float margin_g = g4val - m5;

        unsigned long long chosen = 0ull;
        const size_t obase = (size_t)(tok0 + t) * TOPK;
        float vals[TOPK + 1];
        for (int r = 0; r < TOPK + 1; ++r) {
            float best = NEG_INF; int bi = 0;
            for (int e = 0; e < NEXP; ++e) {
                float v = ((gmask >> (e >> 3)) & 1u) ? sS[t][e] : 0.0f;
                if ((chosen >> e) & 1ull) v = NEG_INF;
                if (v > best) { best = v; bi = e; }
            }
            vals[r] = best;
            if (r < TOPK) {
                chosen |= 1ull << (unsigned)bi;
                out_w[obase + r] = ((gmask >> (bi >> 3)) & 1u) ? sWt[t][bi] : 0.0f;
                out_i[obase + r] = (float)bi;
            }
        }
        float margin_e = 1e30f;
#pragma unroll
        for (int r = 0; r < TOPK; ++r) {
            const float d = vals[r] - vals[r + 1];
            if (d < margin_e) margin_e = d;
        }

        if (margin_g < TAU_G || margin_e < TAU_E) {
            const int slot = atomicAdd(wl, 1);
            wl[WLOFF + slot] = tok0 + t;
        }
    }
}

// ---------------- kernel 2: fp64 exact fixup for flagged tokens ----------------
__global__ __launch_bounds__(256) void gate_fix_kernel(
    const float* __restrict__ x,
    const float* __restrict__ W,
    const float* __restrict__ b,
    const float* __restrict__ bias,
    float* __restrict__ out_w,
    float* __restrict__ out_i,
    const int* __restrict__ wl)
{
    const int count = wl[0];
    const int base  = blockIdx.x * T2;
    if (base >= count) return;

    __shared__ double sPart[T2][NEXP][4];   // 16 KB
    __shared__ float  sS2[T2][NEXP];
    __shared__ float  sW2[T2][NEXP];
    __shared__ int    stok[T2];

    const int tid = threadIdx.x;
    if (tid < T2) {
        int idx = base + tid;
        if (idx >= count) idx = count - 1;   // clamp; writes guarded below
        stok[tid] = wl[WLOFF + idx];
    }
    __syncthreads();

    // thread (e, s): expert e = tid>>2, K-stripe s = tid&3
    const int e = tid >> 2;
    const int s = tid & 3;
    const float4* Wp = (const float4*)(W + (size_t)e * DIM);
    const float4* Xp[T2];
#pragma unroll
    for (int t = 0; t < T2; ++t)
        Xp[t] = (const float4*)(x + (size_t)stok[t] * DIM);

    double acc[T2] = {0., 0., 0., 0., 0., 0., 0., 0.};
    for (int m = 0; m < DIM / 16; ++m) {     // 128 iterations
        const int c = m * 4 + s;
        const float4 wv = Wp[c];
#pragma unroll
        for (int t = 0; t < T2; ++t) {
            const float4 xv = Xp[t][c];
            acc[t] = fma((double)xv.x, (double)wv.x, acc[t]);
            acc[t] = fma((double)xv.y, (double)wv.y, acc[t]);
            acc[t] = fma((double)xv.z, (double)wv.z, acc[t]);
            acc[t] = fma((double)xv.w, (double)wv.w, acc[t]);
        }
    }
#pragma unroll
    for (int t = 0; t < T2; ++t)
        sPart[t][e][s] = acc[t];
    __syncthreads();

    if (tid < NEXP) {
        const double bb = (double)b[tid];
        const float  bi = bias[tid];
#pragma unroll
        for (int t = 0; t < T2; ++t) {
            const double logit = sPart[t][tid][0] + sPart[t][tid][1]
                               + sPart[t][tid][2] + sPart[t][tid][3] + bb;
            const float wv = (float)(1.0 / (1.0 + exp(-logit)));
            sW2[t][tid] = wv;
            sS2[t][tid] = wv + bi;
        }
    }
    __syncthreads();

    if (tid < T2 && base + tid < count) {
        const int t = tid;
        const int tok = stok[t];

        float gs[NGRP];
#pragma unroll
        for (int g = 0; g < NGRP; ++g) {
            float m1 = NEG_INF, m2 = NEG_INF;
#pragma unroll
            for (int j = 0; j < GSIZE; ++j) {
                const float v = sS2[t][g * GSIZE + j];
                if (v > m1) { m2 = m1; m1 = v; }
                else if (v > m2) { m2 = v; }
            }
            gs[g] = m1 + m2;
        }

        unsigned gmask = 0u;
        for (int r = 0; r < TOPKG; ++r) {
            float best = NEG_INF; int bi = 0;
#pragma unroll
            for (int g = 0; g < NGRP; ++g) {
                const float v = ((gmask >> g) & 1u) ? NEG_INF : gs[g];
                if (v > best) { best = v; bi = g; }
            }
            gmask |= 1u << bi;
        }

        unsigned long long chosen = 0ull;
        const size_t obase = (size_t)tok * TOPK;
        for (int r = 0; r < TOPK; ++r) {
            float best = NEG_INF; int bi = 0;
            for (int e2 = 0; e2 < NEXP; ++e2) {
                float v = ((gmask >> (e2 >> 3)) & 1u) ? sS2[t][e2] : 0.0f;
                if ((chosen >> e2) & 1ull) v = NEG_INF;
                if (v > best) { best = v; bi = e2; }
            }
            chosen |= 1ull << (unsigned)bi;
            out_w[obase + r] = ((gmask >> (bi >> 3)) & 1u) ? sW2[t][bi] : 0.0f;
            out_i[obase + r] = (float)bi;
        }
    }
}

extern "C" void kernel_launch(void* const* d_in, const int* in_sizes, int n_in,
                              void* d_out, int out_size, void* d_ws, size_t ws_size,
                              hipStream_t stream) {
    const float* x    = (const float*)d_in[0];
    const float* W    = (const float*)d_in[1];
    const float* b    = (const float*)d_in[2];
    const float* bias = (const float*)d_in[3];

    const int n = in_sizes[0] / DIM;   // 16384 tokens
    float* out_w = (float*)d_out;
    float* out_i = out_w + (size_t)n * TOPK;
    int*   wl    = (int*)d_ws;         // [0]=count, [WLOFF..]=token ids

    zero_wl_kernel<<<1, 64, 0, stream>>>(wl);
    gate_f32_kernel<<<dim3(n / TM), dim3(TPB), 0, stream>>>(
        x, W, b, bias, out_w, out_i, wl);
    gate_fix_kernel<<<dim3((n + T2 - 1) / T2), dim3(256), 0, stream>>>(
        x, W, b, bias, out_w, out_i, wl);
}

// Round 4
// 298.475 us; speedup vs baseline: 1.6188x; 1.6188x over previous
//
#include <hip/hip_runtime.h>
#include <math.h>

#define DIM   2048
#define NEXP  64
#define NGRP  8
#define GSIZE 8
#define TOPK  8
#define TOPKG 4

// ---- kernel 1 geometry: TM=64 tokens/block, K-split 4 ways, 16 waves/block
#define TM    64
#define TK    16
#define NQ    4
#define KQ    (DIM / NQ)     // 512
#define NTQ   (KQ / TK)      // 32 tiles per quarter
#define TPB1  1024

// margin thresholds (fp32 score scale). Accumulation error ~3e-7 rms on
// logits; TAU ~100x safety. Measured flag rate round-3: ~2.4%.
#define TAU_E 4e-5f
#define TAU_G 8e-5f
#define NEG_INF (-3.4e38f)
#define WLOFF 16

// ---- LDS layout (bytes), kernel 1. Quarter tile buffers are dead after the
// K-loop, so the merge scratch aliases them.
#define SA_STRIDE (TM + 4)       // 68 floats -> 16B-aligned rows
#define SB_STRIDE (NEXP + 4)     // 68
#define QBYTES    (TK * SA_STRIDE * 4 + TK * SB_STRIDE * 4)   // 8704
#define SS_OFF    (NQ * QBYTES)                               // 34816
#define SMEM_BYTES (SS_OFF + TM * 65 * 4)                     // 51456 < 64 KB

__global__ void zero_wl_kernel(int* wl) {
    if (threadIdx.x < WLOFF) wl[threadIdx.x] = 0;
}

// ---------------- kernel 1: fp32 GEMM (K-split-4) + routing + margin flag ---
__global__ __launch_bounds__(TPB1, 4) void gate_f32_kernel(
    const float* __restrict__ x,
    const float* __restrict__ W,
    const float* __restrict__ b,
    const float* __restrict__ bias,
    float* __restrict__ out_w,
    float* __restrict__ out_i,
    int* __restrict__ wl)
{
    __shared__ __align__(16) char smem[SMEM_BYTES];

    const int tid = threadIdx.x;
    const int q   = tid >> 8;          // K-quarter 0..3 (4 waves each)
    const int i2  = tid & 255;
    const int tok0 = blockIdx.x * TM;

    float (*sA)[SA_STRIDE] = (float (*)[SA_STRIDE])(smem + q * QBYTES);
    float (*sB)[SB_STRIDE] = (float (*)[SB_STRIDE])(smem + q * QBYTES + TK * SA_STRIDE * 4);
    float (*Mrg0)[NEXP]    = (float (*)[NEXP])(smem);            // 16 KB, aliases tiles
    float (*Mrg1)[NEXP]    = (float (*)[NEXP])(smem + 16384);    // 16 KB, aliases tiles
    float (*sS)[65]        = (float (*)[65])(smem + SS_OFF);     // score table

    // staging: 256 threads/quarter; x tile 64 rows x 4 f4-cols, W tile same
    const int c4 = i2 & 3;
    const int k0 = c4 * 4;
    const int r  = i2 >> 2;            // 0..63 (token row / expert row)
    // compute mapping: 4 tokens x 4 experts per thread
    const int ty = i2 >> 4;            // 0..15
    const int tx = i2 & 15;            // 0..15

    const float* xp = x + (size_t)(tok0 + r) * DIM + q * KQ + k0;
    const float* wp = W + (size_t)r * DIM + q * KQ + k0;

    float4 pa = *(const float4*)xp;
    float4 pw = *(const float4*)wp;

    float acc[4][4] = {{0.f,0.f,0.f,0.f},{0.f,0.f,0.f,0.f},
                       {0.f,0.f,0.f,0.f},{0.f,0.f,0.f,0.f}};

    for (int it = 0; it < NTQ; ++it) {
        sA[k0+0][r] = pa.x; sA[k0+1][r] = pa.y;
        sA[k0+2][r] = pa.z; sA[k0+3][r] = pa.w;
        sB[k0+0][r] = pw.x; sB[k0+1][r] = pw.y;
        sB[k0+2][r] = pw.z; sB[k0+3][r] = pw.w;
        __syncthreads();

        if (it + 1 < NTQ) {
            pa = *(const float4*)(xp + (it + 1) * TK);
            pw = *(const float4*)(wp + (it + 1) * TK);
        }

        float at[4][4] = {{0.f,0.f,0.f,0.f},{0.f,0.f,0.f,0.f},
                          {0.f,0.f,0.f,0.f},{0.f,0.f,0.f,0.f}};
#pragma unroll
        for (int kk = 0; kk < TK; ++kk) {
            float4 av = *(const float4*)&sA[kk][ty * 4];
            float4 bv = *(const float4*)&sB[kk][tx * 4];
            float a4[4] = {av.x, av.y, av.z, av.w};
            float b4[4] = {bv.x, bv.y, bv.z, bv.w};
#pragma unroll
            for (int i = 0; i < 4; ++i)
#pragma unroll
                for (int j = 0; j < 4; ++j)
                    at[i][j] += a4[i] * b4[j];
        }
#pragma unroll
        for (int i = 0; i < 4; ++i)
#pragma unroll
            for (int j = 0; j < 4; ++j)
                acc[i][j] += at[i][j];
        __syncthreads();
    }

    // ---- merge quarters through LDS (tile buffers now dead) ----
    // final order: ((q0+q1) + (q2+q3)) + b
    if (q == 1 || q == 3) {
        float (*M)[NEXP] = (q == 1) ? Mrg0 : Mrg1;
#pragma unroll
        for (int i = 0; i < 4; ++i) {
            float4 v = {acc[i][0], acc[i][1], acc[i][2], acc[i][3]};
            *(float4*)&M[ty * 4 + i][tx * 4] = v;
        }
    }
    __syncthreads();
    if (q == 0 || q == 2) {
        float (*M)[NEXP] = (q == 0) ? Mrg0 : Mrg1;
#pragma unroll
        for (int i = 0; i < 4; ++i) {
            float4 v = *(const float4*)&M[ty * 4 + i][tx * 4];
            acc[i][0] += v.x; acc[i][1] += v.y; acc[i][2] += v.z; acc[i][3] += v.w;
        }
    }
    __syncthreads();
    if (q == 2) {
#pragma unroll
        for (int i = 0; i < 4; ++i) {
            float4 v = {acc[i][0], acc[i][1], acc[i][2], acc[i][3]};
            *(float4*)&Mrg0[ty * 4 + i][tx * 4] = v;
        }
    }
    __syncthreads();
    if (q == 0) {
        float bv4[4], bi4[4];
#pragma unroll
        for (int j = 0; j < 4; ++j) {
            bv4[j] = b[tx * 4 + j];
            bi4[j] = bias[tx * 4 + j];
        }
#pragma unroll
        for (int i = 0; i < 4; ++i) {
            const int t = ty * 4 + i;
            float4 v = *(const float4*)&Mrg0[t][tx * 4];
            float s4[4] = {v.x, v.y, v.z, v.w};
#pragma unroll
            for (int j = 0; j < 4; ++j) {
                const float logit = (acc[i][j] + s4[j]) + bv4[j];
                const float wv = 1.0f / (1.0f + expf(-logit));
                sS[t][tx * 4 + j] = wv + bi4[j];
            }
        }
    }
    __syncthreads();

    // ---- routing + margin flagging: thread t per token ----
    if (tid < TM) {
        const int t = tid;

        float gs[NGRP];
#pragma unroll
        for (int g = 0; g < NGRP; ++g) {
            float m1 = NEG_INF, m2 = NEG_INF;
#pragma unroll
            for (int j = 0; j < GSIZE; ++j) {
                const float v = sS[t][g * GSIZE + j];
                if (v > m1) { m2 = m1; m1 = v; }
                else if (v > m2) { m2 = v; }
            }
            gs[g] = m1 + m2;
        }

        unsigned gmask = 0u;
        float g4val = NEG_INF;
        for (int rr = 0; rr < TOPKG; ++rr) {
            float best = NEG_INF; int bi = 0;
#pragma unroll
            for (int g = 0; g < NGRP; ++g) {
                const float v = ((gmask >> g) & 1u) ? NEG_INF : gs[g];
                if (v > best) { best = v; bi = g; }
            }
            gmask |= 1u << bi;
            g4val = best;
        }
        float m5 = NEG_INF;
#pragma unroll
        for (int g = 0; g < NGRP; ++g)
            if (!((gmask >> g) & 1u) && gs[g] > m5) m5 = gs[g];
        const float margin_g = g4val - m5;

        unsigned long long chosen = 0ull;
        const size_t obase = (size_t)(tok0 + t) * TOPK;
        float vals[TOPK + 1];
        for (int rr = 0; rr < TOPK + 1; ++rr) {
            float best = NEG_INF; int bi = 0;
            for (int e = 0; e < NEXP; ++e) {
                float v = ((gmask >> (e >> 3)) & 1u) ? sS[t][e] : 0.0f;
                if ((chosen >> e) & 1ull) v = NEG_INF;
                if (v > best) { best = v; bi = e; }
            }
            vals[rr] = best;
            if (rr < TOPK) {
                chosen |= 1ull << (unsigned)bi;
                // weight = sigmoid = score - bias (exact for bias=0; <=1ulp else)
                out_w[obase + rr] = ((gmask >> (bi >> 3)) & 1u)
                                  ? (sS[t][bi] - bias[bi]) : 0.0f;
                out_i[obase + rr] = (float)bi;
            }
        }
        float margin_e = 1e30f;
#pragma unroll
        for (int rr = 0; rr < TOPK; ++rr) {
            const float d = vals[rr] - vals[rr + 1];
            if (d < margin_e) margin_e = d;
        }

        if (margin_g < TAU_G || margin_e < TAU_E) {
            const int slot = atomicAdd(wl, 1);
            wl[WLOFF + slot] = tok0 + t;
        }
    }
}

// ---------------- kernel 2: fp64 exact fixup, 1 token per iteration ---------
__global__ __launch_bounds__(256) void gate_fix_kernel(
    const float* __restrict__ x,
    const float* __restrict__ W,
    const float* __restrict__ b,
    const float* __restrict__ bias,
    float* __restrict__ out_w,
    float* __restrict__ out_i,
    const int* __restrict__ wl)
{
    const int count = wl[0];

    __shared__ __align__(16) float sX[DIM];   // 8 KB token row
    __shared__ double sPart[NEXP][4];
    __shared__ float  sS2[NEXP], sW2[NEXP];

    const int tid = threadIdx.x;
    const int e   = tid >> 2;     // expert
    const int s   = tid & 3;      // K-stripe (interleaved: c = m*4+s)

    for (int widx = blockIdx.x; widx < count; widx += (int)gridDim.x) {
        const int tok = wl[WLOFF + widx];

        // stage x row into LDS (coalesced float4)
        const float4* xr = (const float4*)(x + (size_t)tok * DIM);
        ((float4*)sX)[tid]       = xr[tid];
        ((float4*)sX)[tid + 256] = xr[tid + 256];
        __syncthreads();

        const float4* Wr = (const float4*)(W + (size_t)e * DIM);
        double a0 = 0., a1 = 0., a2 = 0., a3 = 0.;   // 4 independent chains
#pragma unroll 8
        for (int m = 0; m < DIM / 16; ++m) {         // 128 iterations
            const int c = m * 4 + s;
            const float4 wv = Wr[c];
            const float4 xv = ((const float4*)sX)[c];
            a0 = fma((double)xv.x, (double)wv.x, a0);
            a1 = fma((double)xv.y, (double)wv.y, a1);
            a2 = fma((double)xv.z, (double)wv.z, a2);
            a3 = fma((double)xv.w, (double)wv.w, a3);
        }
        sPart[e][s] = (a0 + a1) + (a2 + a3);
        __syncthreads();

        if (tid < NEXP) {
            const double logit = ((sPart[tid][0] + sPart[tid][1])
                                + (sPart[tid][2] + sPart[tid][3])) + (double)b[tid];
            const float wv = (float)(1.0 / (1.0 + exp(-logit)));
            sW2[tid] = wv;
            sS2[tid] = wv + bias[tid];
        }
        __syncthreads();

        if (tid == 0) {
            float gs[NGRP];
#pragma unroll
            for (int g = 0; g < NGRP; ++g) {
                float m1 = NEG_INF, m2 = NEG_INF;
#pragma unroll
                for (int j = 0; j < GSIZE; ++j) {
                    const float v = sS2[g * GSIZE + j];
                    if (v > m1) { m2 = m1; m1 = v; }
                    else if (v > m2) { m2 = v; }
                }
                gs[g] = m1 + m2;
            }
            unsigned gmask = 0u;
            for (int rr = 0; rr < TOPKG; ++rr) {
                float best = NEG_INF; int bi = 0;
#pragma unroll
                for (int g = 0; g < NGRP; ++g) {
                    const float v = ((gmask >> g) & 1u) ? NEG_INF : gs[g];
                    if (v > best) { best = v; bi = g; }
                }
                gmask |= 1u << bi;
            }
            unsigned long long chosen = 0ull;
            const size_t obase = (size_t)tok * TOPK;
            for (int rr = 0; rr < TOPK; ++rr) {
                float best = NEG_INF; int bi = 0;
                for (int e2 = 0; e2 < NEXP; ++e2) {
                    float v = ((gmask >> (e2 >> 3)) & 1u) ? sS2[e2] : 0.0f;
                    if ((chosen >> e2) & 1ull) v = NEG_INF;
                    if (v > best) { best = v; bi = e2; }
                }
                chosen |= 1ull << (unsigned)bi;
                out_w[obase + rr] = ((gmask >> (bi >> 3)) & 1u) ? sW2[bi] : 0.0f;
                out_i[obase + rr] = (float)bi;
            }
        }
        __syncthreads();
    }
}

extern "C" void kernel_launch(void* const* d_in, const int* in_sizes, int n_in,
                              void* d_out, int out_size, void* d_ws, size_t ws_size,
                              hipStream_t stream) {
    const float* x    = (const float*)d_in[0];
    const float* W    = (const float*)d_in[1];
    const float* b    = (const float*)d_in[2];
    const float* bias = (const float*)d_in[3];

    const int n = in_sizes[0] / DIM;   // 16384 tokens
    float* out_w = (float*)d_out;
    float* out_i = out_w + (size_t)n * TOPK;
    int*   wl    = (int*)d_ws;         // [0]=count, [WLOFF..]=token ids

    zero_wl_kernel<<<1, 64, 0, stream>>>(wl);
    gate_f32_kernel<<<dim3(n / TM), dim3(TPB1), 0, stream>>>(
        x, W, b, bias, out_w, out_i, wl);
    gate_fix_kernel<<<dim3(1024), dim3(256), 0, stream>>>(
        x, W, b, bias, out_w, out_i, wl);
}